// Round 8
// baseline (506.934 us; speedup 1.0000x reference)
//
#include <hip/hip_runtime.h>
#include <math.h>

#define NN 100000
#define NE 3200000
#define INF 384
#define HID 64
#define CAP 48
#define OVF_CAP 65536
#define NBIN 391            // bin = col >> 8 (256 nodes per bin)
#define NREP 8              // replicas per bin (blockIdx & 7 ~ XCD id)
#define NCTR (NBIN * NREP)  // 3128
#define BCAP 1536           // fixed slots per (bin,rep); mean 1023, 16-sigma margin
#define EPB 8192            // edges per block (scatter chunk)
#define NBLK ((NE + EPB - 1) / EPB)  // 391

typedef unsigned long long ulong64;
typedef unsigned int uint32;
typedef unsigned short ushort16;
typedef __attribute__((ext_vector_type(8))) short bf16x8;
typedef __attribute__((ext_vector_type(4))) float f32x4;

__device__ inline float bf16_to_f(uint32 us) { return __uint_as_float(us << 16); }
__device__ inline ushort16 f_to_bf16(float f) {
    uint32 u = __float_as_uint(f);
    u += 0x7FFF + ((u >> 16) & 1);  // round-to-nearest-even
    return (ushort16)(u >> 16);
}
// split x into bf16 hi + bf16 lo (x ~= hi + lo, residual ~2^-17 relative)
__device__ inline void split_bf16(float x, ushort16& h, ushort16& l) {
    h = f_to_bf16(x);
    float hf = bf16_to_f((uint32)h);
    l = f_to_bf16(x - hf);
}

// ---------------- setup: counters + W pre-split (fused, one launch) ----------
// bincur[i] = i*BCAP gives every (bin,rep) counter a fixed private region in
// ebin -- replaces binhist+binscan (uniform-random cols -> Poisson(1023) per
// counter vs capacity 1536 = 16 sigma).
// W layout: element (k,j) of W[K][64] -> ushort idx
//   ((k>>5)*4 + (j>>4))*64 + ((j&15) | (((k>>3)&3)<<4)) -> *8 + (k&7)
// so a wave's B-fragment load is one contiguous 1KB transaction.

__global__ __launch_bounds__(256) void setup_kernel(const float* __restrict__ W1,
                                                    const float* __restrict__ W2,
                                                    const float* __restrict__ Wm1,
                                                    ushort16* __restrict__ wp1h,
                                                    ushort16* __restrict__ wp1l,
                                                    ushort16* __restrict__ wp2h,
                                                    ushort16* __restrict__ wp2l,
                                                    ushort16* __restrict__ wpm1h,
                                                    ushort16* __restrict__ wpm1l,
                                                    int* __restrict__ ovf_cnt,
                                                    int* __restrict__ bincur) {
    int i = blockIdx.x * blockDim.x + threadIdx.x;
    int np = gridDim.x * blockDim.x;
    if (i == 0) *ovf_cnt = 0;
    for (int idx = i; idx < NCTR; idx += np) bincur[idx] = idx * BCAP;
    for (int idx = i; idx < INF * HID; idx += np) {
        int k = idx >> 6, j = idx & 63;
        ushort16 h, l;
        split_bf16(W1[idx], h, l);
        size_t dst = ((size_t)(((k >> 5) * 4 + (j >> 4)) * 64 +
                               ((j & 15) | (((k >> 3) & 3) << 4))) << 3) + (k & 7);
        wp1h[dst] = h;
        wp1l[dst] = l;
    }
    for (int idx = i; idx < HID * HID; idx += np) {
        int k = idx >> 6, j = idx & 63;
        size_t dst = ((size_t)(((k >> 5) * 4 + (j >> 4)) * 64 +
                               ((j & 15) | (((k >> 3) & 3) << 4))) << 3) + (k & 7);
        ushort16 h, l;
        split_bf16(W2[idx], h, l);
        wp2h[dst] = h;
        wp2l[dst] = l;
        split_bf16(Wm1[idx], h, l);
        wpm1h[dst] = h;
        wpm1l[dst] = l;
    }
}

// ---------------- scatter edges into fixed (bin,rep) regions ----------------

__global__ __launch_bounds__(1024) void binscatter_kernel(const int* __restrict__ row,
                                                          const int* __restrict__ col,
                                                          const float* __restrict__ ew,
                                                          int* __restrict__ bincur,
                                                          ulong64* __restrict__ ebin) {
    __shared__ int lhist[NBIN];
    __shared__ int lbase[NBIN];
    int tid = threadIdx.x;
    int rep = blockIdx.x & (NREP - 1);
    int base = blockIdx.x * EPB;
    if (tid < NBIN) lhist[tid] = 0;
    __syncthreads();
    int brk[8], rr[8];
    uint32 wb[8];
#pragma unroll
    for (int i = 0; i < 8; i++) {
        int e = base + i * 1024 + tid;
        brk[i] = -1;
        if (e < NE) {
            int r = row[e];
            int c = col[e];
            wb[i] = __float_as_uint(ew[e]);
            int b = c >> 8;
            int rk = atomicAdd(&lhist[b], 1);
            brk[i] = (b << 16) | rk;
            rr[i] = r | ((c & 255) << 17);
        }
    }
    __syncthreads();
    if (tid < NBIN && lhist[tid] > 0)
        lbase[tid] = atomicAdd(&bincur[tid * NREP + rep], lhist[tid]);
    __syncthreads();
#pragma unroll
    for (int i = 0; i < 8; i++) {
        if (brk[i] >= 0) {
            int b = brk[i] >> 16;
            int pos = lbase[b] + (brk[i] & 0xFFFF);
            int lim = (b * NREP + rep + 1) * BCAP;
            if (pos < lim)  // 16-sigma safety clamp, effectively never taken
                ebin[pos] = ((ulong64)wb[i] << 32) | (uint32)rr[i];
        }
    }
}

// ---------------- buckets + degree + dis (256-node bins, 8 segments) ---------
// Pads each node's sedge slots to a multiple of 8 with zeros so the aggregate
// can run an unguarded 8-wide loop (pad slots: w=0, r=0 -> contribute 0).

__global__ __launch_bounds__(256) void bucket_kernel(const int* __restrict__ bincur,
                                                     const ulong64* __restrict__ ebin,
                                                     ulong64* __restrict__ sedge,
                                                     int* __restrict__ cnt,
                                                     float* __restrict__ dis,
                                                     int* __restrict__ ovf_cnt,
                                                     int4* __restrict__ ovf) {
    __shared__ int cur[256];
    __shared__ float sdeg[256];
    int bin = blockIdx.x;
    int node0 = bin << 8;
    cur[threadIdx.x] = 0;
    sdeg[threadIdx.x] = 0.f;
    __syncthreads();
    for (int rep = 0; rep < NREP; rep++) {
        int ctr = bin * NREP + rep;
        int start = ctr * BCAP;
        int end = min(bincur[ctr], start + BCAP);
        for (int i = start + threadIdx.x; i < end; i += 256) {
            ulong64 pk = ebin[i];
            int r = (int)(pk & 0x1FFFF);
            int lc = (int)((pk >> 17) & 255);
            uint32 wb = (uint32)(pk >> 32);
            atomicAdd(&sdeg[lc], __uint_as_float(wb));   // LDS float atomic
            int rank = atomicAdd(&cur[lc], 1);           // LDS int atomic
            int node = node0 + lc;
            if (rank < CAP) {
                sedge[(size_t)node * CAP + rank] = ((ulong64)wb << 32) | (uint32)r;
            } else {
                int o = atomicAdd(ovf_cnt, 1);
                if (o < OVF_CAP) ovf[o] = make_int4(r, node, (int)wb, 0);
            }
        }
    }
    __syncthreads();
    int node = node0 + threadIdx.x;
    if (node < NN) {
        int cc = min(cur[threadIdx.x], CAP);
        cnt[node] = cc;
        int cpad = min((cc + 7) & ~7, CAP);
        for (int s = cc; s < cpad; s++) sedge[(size_t)node * CAP + s] = 0;
        dis[node] = rsqrtf(sdeg[threadIdx.x] + 1.0f);  // +1 self-loop
    }
}

// ---------------- MFMA GEMM (no LDS/barriers, deep pipeline) -----------------
// hs_bf16[N x 64] = dis[N] * (act(A[N x K]) @ W).
// R7's VGPR=32 forced load->waitcnt(0)->use serialization (~120 round trips
// per thread). Fix: M=32 rows/wave (2 A-frags, 2x B amortization), all 8
// B-loads for an iteration issued in one batch at iteration top (latency
// hides under the 2-frag bf16-split convert), A double-buffered one K-step
// ahead, __launch_bounds__(256,3) gives the register headroom (grid 782 =
// 3.05 blocks/CU = exactly 3 waves/SIMD).
// 3-term bf16 split (Ah*Wh + Al*Wh + Ah*Wl), fp32 accumulate.
// mfma_f32_16x16x32_bf16: A row=lane&15, k=(lane>>4)*8+j (8 consecutive
// floats of one row -> direct global load); D col=lane&15, row=(lane>>4)*4+reg.

template <int K, bool LEAKY>
__global__ __launch_bounds__(256, 3) void mfma_gemm_kernel(const float* __restrict__ A,
                                                           const ushort16* __restrict__ Wph,
                                                           const ushort16* __restrict__ Wpl,
                                                           const float* __restrict__ dis,
                                                           ushort16* __restrict__ out) {
    const int tid = threadIdx.x;
    const int w = tid >> 6;
    const int l = tid & 63;
    const int lrow = l & 15;
    const int kq = (l >> 4) * 8;  // float offset within a 32-k step
    const int nb = blockIdx.x * 128;
    const int wr = nb + w * 32;
    const bf16x8* __restrict__ Bh = (const bf16x8*)Wph;
    const bf16x8* __restrict__ Bl = (const bf16x8*)Wpl;
    const float* __restrict__ ar0 = A + (size_t)min(wr + lrow, NN - 1) * K + kq;
    const float* __restrict__ ar1 = A + (size_t)min(wr + 16 + lrow, NN - 1) * K + kq;

    f32x4 acc[2][4];
#pragma unroll
    for (int m = 0; m < 2; m++)
#pragma unroll
        for (int n = 0; n < 4; n++) acc[m][n] = (f32x4){0.f, 0.f, 0.f, 0.f};

    constexpr int NS = K / 32;
    // A double-buffer: current K-step in registers
    float4 a0[2], a1[2];
    a0[0] = *(const float4*)(ar0);
    a1[0] = *(const float4*)(ar0 + 4);
    a0[1] = *(const float4*)(ar1);
    a1[1] = *(const float4*)(ar1 + 4);

#pragma unroll
    for (int ks = 0; ks < NS; ks++) {
        // ---- batch-issue this iteration's 8 B-loads + next K-step's A ----
        bf16x8 bhc[4], blc[4];
#pragma unroll
        for (int n = 0; n < 4; n++) {
            bhc[n] = Bh[(size_t)(ks * 4 + n) * 64 + l];
            blc[n] = Bl[(size_t)(ks * 4 + n) * 64 + l];
        }
        float4 p0[2], p1[2];
        if (ks + 1 < NS) {
            p0[0] = *(const float4*)(ar0 + (ks + 1) * 32);
            p1[0] = *(const float4*)(ar0 + (ks + 1) * 32 + 4);
            p0[1] = *(const float4*)(ar1 + (ks + 1) * 32);
            p1[1] = *(const float4*)(ar1 + (ks + 1) * 32 + 4);
        }
        // ---- convert A (VALU) -- overlaps the outstanding B loads ----
        bf16x8 ah[2], al[2];
#pragma unroll
        for (int m = 0; m < 2; m++) {
            float av[8] = {a0[m].x, a0[m].y, a0[m].z, a0[m].w,
                           a1[m].x, a1[m].y, a1[m].z, a1[m].w};
#pragma unroll
            for (int i = 0; i < 8; i++) {
                float x = av[i];
                if (LEAKY) x = x > 0.f ? x : 0.01f * x;
                ushort16 hh, ll;
                split_bf16(x, hh, ll);
                ah[m][i] = (short)hh;
                al[m][i] = (short)ll;
            }
        }
        // ---- 24 MFMAs (2 M-frags x 4 N-frags x 3 split terms) ----
#pragma unroll
        for (int n = 0; n < 4; n++)
#pragma unroll
            for (int m = 0; m < 2; m++) {
                acc[m][n] = __builtin_amdgcn_mfma_f32_16x16x32_bf16(ah[m], bhc[n], acc[m][n], 0, 0, 0);
                acc[m][n] = __builtin_amdgcn_mfma_f32_16x16x32_bf16(al[m], bhc[n], acc[m][n], 0, 0, 0);
                acc[m][n] = __builtin_amdgcn_mfma_f32_16x16x32_bf16(ah[m], blc[n], acc[m][n], 0, 0, 0);
            }
        if (ks + 1 < NS) {
#pragma unroll
            for (int m = 0; m < 2; m++) {
                a0[m] = p0[m];
                a1[m] = p1[m];
            }
        }
    }
    // ---- epilogue: D col=lane&15, row=(lane>>4)*4+reg; scale by dis[node] ----
#pragma unroll
    for (int m = 0; m < 2; m++) {
        int rbase = wr + m * 16 + (l >> 4) * 4;
#pragma unroll
        for (int r = 0; r < 4; r++) {
            int node = rbase + r;
            if (node < NN) {
                float ds = dis[node];
#pragma unroll
                for (int n = 0; n < 4; n++)
                    out[(size_t)node * HID + n * 16 + lrow] = f_to_bf16(acc[m][n][r] * ds);
            }
        }
    }
}

// ---------------- bucket aggregate: wave per node, lane = feature ----------------
// hs is dis-prescaled bf16. n is made provably wave-uniform via readfirstlane
// so the 8-slot packet loads become scalar-cache loads; packet j+1's scalar
// loads issue before packet j's gathers.
// out[n] = bias + dis[n] * (hs[n] + sum_j w_j * hs[r_j])

__global__ __launch_bounds__(256) void aggregate_kernel(const int* __restrict__ cnt,
                                                        const ulong64* __restrict__ sedge,
                                                        const float* __restrict__ dis,
                                                        const ushort16* __restrict__ hs,
                                                        const float* __restrict__ bias,
                                                        float* __restrict__ out) {
    int lane = threadIdx.x & 63;
    int wslot = __builtin_amdgcn_readfirstlane(threadIdx.x >> 6);
    int n = blockIdx.x * 4 + wslot;
    if (n >= NN) return;
    int c = cnt[n];                      // uniform -> scalar load
    int cpad = (c + 7) & ~7;
    float dn = dis[n];                   // uniform -> scalar load
    const ulong64* __restrict__ el = sedge + (size_t)n * CAP;

    float acc = bf16_to_f((uint32)hs[(size_t)n * HID + lane]);  // self term
    if (cpad > 0) {
        ulong64 p[8];
#pragma unroll
        for (int i = 0; i < 8; i++) p[i] = el[i];
        int j = 0;
        for (;;) {
            int jn = j + 8;
            bool more = jn < cpad;
            ulong64 q[8];
            if (more) {
#pragma unroll
                for (int i = 0; i < 8; i++) q[i] = el[jn + i];
            }
            float v[8], wv[8];
#pragma unroll
            for (int i = 0; i < 8; i++) {
                uint32 r = (uint32)p[i];
                wv[i] = __uint_as_float((uint32)(p[i] >> 32));  // 0 for pad slots
                v[i] = bf16_to_f((uint32)hs[(size_t)r * HID + lane]);
            }
#pragma unroll
            for (int i = 0; i < 8; i++) acc = fmaf(wv[i], v[i], acc);
            if (!more) break;
            j = jn;
#pragma unroll
            for (int i = 0; i < 8; i++) p[i] = q[i];
        }
    }
    out[(size_t)n * HID + lane] = fmaf(dn, acc, bias[lane]);
}

// ---------------- overflow edges: rare, fp32 atomics ----------------
// hs is dis-prescaled: contribution = dis[dst] * w * hs[src]

__global__ __launch_bounds__(256) void ovf_kernel(const int* __restrict__ ovf_cnt,
                                                  const int4* __restrict__ ovf,
                                                  const float* __restrict__ dis,
                                                  const ushort16* __restrict__ hs,
                                                  float* __restrict__ out) {
    int lane = threadIdx.x & 63;
    int wid = blockIdx.x * 4 + (threadIdx.x >> 6);
    int nw = gridDim.x * 4;
    int c = min(*ovf_cnt, OVF_CAP);
    for (int i = wid; i < c; i += nw) {
        int4 t = ovf[i];
        float w = __int_as_float(t.z);
        float nrm = w * dis[t.y];
        atomicAdd(&out[(size_t)t.y * HID + lane],
                  nrm * bf16_to_f((uint32)hs[(size_t)t.x * HID + lane]));
    }
}

// ---------------- MLP head + softmax (no LDS, deep pipeline) -----------------
// agg[N x 64] -> (ELU(agg@Wm1 + bm1)) @ Wm2 + bm2 -> softmax(2).
// M=32/wave like the GEMM; K=64 so ALL 16 B-fragment pairs preload up front
// (zero B latency in the loop); all 8 A float4 batched.

__global__ __launch_bounds__(256, 3) void mlp_mfma_kernel(const float* __restrict__ agg,
                                                          const ushort16* __restrict__ Wph,
                                                          const ushort16* __restrict__ Wpl,
                                                          const float* __restrict__ bm1,
                                                          const float* __restrict__ Wm2,
                                                          const float* __restrict__ bm2,
                                                          float* __restrict__ out) {
    const int tid = threadIdx.x;
    const int w = tid >> 6;
    const int l = tid & 63;
    const int lrow = l & 15;
    const int kq = (l >> 4) * 8;
    const int nb = blockIdx.x * 128;
    const int wr = nb + w * 32;
    const bf16x8* __restrict__ Bh = (const bf16x8*)Wph;
    const bf16x8* __restrict__ Bl = (const bf16x8*)Wpl;
    const float* __restrict__ ar0 = agg + (size_t)min(wr + lrow, NN - 1) * HID + kq;
    const float* __restrict__ ar1 = agg + (size_t)min(wr + 16 + lrow, NN - 1) * HID + kq;

    // preload ALL B fragments (K=64 -> 8 pairs) and all A
    bf16x8 bh[8], bl[8];
#pragma unroll
    for (int s = 0; s < 8; s++) {
        bh[s] = Bh[(size_t)s * 64 + l];
        bl[s] = Bl[(size_t)s * 64 + l];
    }
    float4 a[2][4];
#pragma unroll
    for (int m = 0; m < 2; m++) {
        const float* ar = m ? ar1 : ar0;
        a[m][0] = *(const float4*)(ar);
        a[m][1] = *(const float4*)(ar + 4);
        a[m][2] = *(const float4*)(ar + 32);
        a[m][3] = *(const float4*)(ar + 36);
    }

    f32x4 acc[2][4];
#pragma unroll
    for (int m = 0; m < 2; m++)
#pragma unroll
        for (int n = 0; n < 4; n++) acc[m][n] = (f32x4){0.f, 0.f, 0.f, 0.f};

#pragma unroll
    for (int ks = 0; ks < 2; ks++) {
        bf16x8 ah[2], al[2];
#pragma unroll
        for (int m = 0; m < 2; m++) {
            float4 x0 = a[m][ks * 2], x1 = a[m][ks * 2 + 1];
            float av[8] = {x0.x, x0.y, x0.z, x0.w, x1.x, x1.y, x1.z, x1.w};
#pragma unroll
            for (int i = 0; i < 8; i++) {
                ushort16 hh, ll;
                split_bf16(av[i], hh, ll);
                ah[m][i] = (short)hh;
                al[m][i] = (short)ll;
            }
        }
#pragma unroll
        for (int n = 0; n < 4; n++)
#pragma unroll
            for (int m = 0; m < 2; m++) {
                acc[m][n] = __builtin_amdgcn_mfma_f32_16x16x32_bf16(ah[m], bh[ks * 4 + n], acc[m][n], 0, 0, 0);
                acc[m][n] = __builtin_amdgcn_mfma_f32_16x16x32_bf16(al[m], bh[ks * 4 + n], acc[m][n], 0, 0, 0);
                acc[m][n] = __builtin_amdgcn_mfma_f32_16x16x32_bf16(ah[m], bl[ks * 4 + n], acc[m][n], 0, 0, 0);
            }
    }

    // per-lane constants for the 4 columns this lane owns
    float b1c[4], w2a[4], w2b[4];
#pragma unroll
    for (int n = 0; n < 4; n++) {
        int colw = n * 16 + lrow;
        b1c[n] = bm1[colw];
        w2a[n] = Wm2[colw * 2];
        w2b[n] = Wm2[colw * 2 + 1];
    }
    float b20 = bm2[0], b21 = bm2[1];

#pragma unroll
    for (int m = 0; m < 2; m++)
#pragma unroll
        for (int r = 0; r < 4; r++) {
            float s0 = 0.f, s1 = 0.f;
#pragma unroll
            for (int n = 0; n < 4; n++) {
                float u = acc[m][n][r] + b1c[n];
                u = u > 0.f ? u : (expf(u) - 1.f);  // ELU
                s0 = fmaf(u, w2a[n], s0);
                s1 = fmaf(u, w2b[n], s1);
            }
#pragma unroll
            for (int off = 1; off < 16; off <<= 1) {
                s0 += __shfl_xor(s0, off);
                s1 += __shfl_xor(s1, off);
            }
            int node = wr + m * 16 + (l >> 4) * 4 + r;
            if (lrow == 0 && node < NN) {
                float l0 = s0 + b20, l1 = s1 + b21;
                float mx = fmaxf(l0, l1);
                float e0 = expf(l0 - mx), e1 = expf(l1 - mx);
                float inv = 1.f / (e0 + e1);
                *(float2*)&out[(size_t)node * 2] = make_float2(e0 * inv, e1 * inv);
            }
        }
}

// ---------------- launch ----------------

extern "C" void kernel_launch(void* const* d_in, const int* in_sizes, int n_in,
                              void* d_out, int out_size, void* d_ws, size_t ws_size,
                              hipStream_t stream) {
    const float* X   = (const float*)d_in[0];
    const int*   ei  = (const int*)d_in[1];
    const float* ew  = (const float*)d_in[2];
    const float* W1  = (const float*)d_in[3];
    const float* b1  = (const float*)d_in[4];
    const float* W2  = (const float*)d_in[5];
    const float* b2  = (const float*)d_in[6];
    const float* Wm1 = (const float*)d_in[7];
    const float* bm1 = (const float*)d_in[8];
    const float* Wm2 = (const float*)d_in[9];
    const float* bm2 = (const float*)d_in[10];
    const int* row = ei;
    const int* col = ei + NE;
    float* out = (float*)d_out;

    const size_t MB = 1024 * 1024;
    const size_t KB = 1024;
    char* ws = (char*)d_ws;
    float*    dis     = (float*)   (ws + 0 * MB);           // NN floats (0.4 MB)
    int*      cnt     = (int*)     (ws + 1 * MB);           // NN ints   (0.4 MB)
    ushort16* wp1h    = (ushort16*)(ws + 2 * MB);           // 48 KB (frag-order)
    ushort16* wp1l    = (ushort16*)(ws + 2 * MB + 64 * KB);
    ushort16* wp2h    = (ushort16*)(ws + 2 * MB + 128 * KB);// 8 KB
    ushort16* wp2l    = (ushort16*)(ws + 2 * MB + 144 * KB);
    ushort16* wpm1h   = (ushort16*)(ws + 2 * MB + 160 * KB);// 8 KB
    ushort16* wpm1l   = (ushort16*)(ws + 2 * MB + 176 * KB);
    int*      ovf_cnt = (int*)     (ws + 3 * MB);           // 1 int
    int*      bincur  = (int*)     (ws + 3 * MB + 16 * KB); // NCTR ints
    int4*     ovf     = (int4*)    (ws + 4 * MB);           // OVF_CAP*16 (1 MB)
    ulong64*  ebin    = (ulong64*) (ws + 5 * MB);           // NCTR*BCAP*8 = 38.4 MB
    float*    h2      = (float*)   (ws + 5 * MB);           // fp32 (25.6MB), overlays ebin
    ulong64*  sedge   = (ulong64*) (ws + 44 * MB);          // NN*CAP*8 = 38.4 MB
    ushort16* h1      = (ushort16*)(ws + 83 * MB);          // NN*64 bf16 (12.8 MB)

    // ---- setup (counters + W pre-split) + direct-alloc scatter + buckets ----
    setup_kernel<<<64, 256, 0, stream>>>(W1, W2, Wm1, wp1h, wp1l, wp2h, wp2l,
                                         wpm1h, wpm1l, ovf_cnt, bincur);
    binscatter_kernel<<<NBLK, 1024, 0, stream>>>(row, col, ew, bincur, ebin);
    bucket_kernel<<<NBIN, 256, 0, stream>>>(bincur, ebin, sedge, cnt, dis, ovf_cnt, ovf);

    // ---- conv1 ----
    mfma_gemm_kernel<INF, false><<<(NN + 127) / 128, 256, 0, stream>>>(X, wp1h, wp1l, dis, h1);
    aggregate_kernel<<<(NN + 3) / 4, 256, 0, stream>>>(cnt, sedge, dis, h1, b1, h2);
    ovf_kernel<<<256, 256, 0, stream>>>(ovf_cnt, ovf, dis, h1, h2);

    // ---- conv2 ----
    mfma_gemm_kernel<HID, true><<<(NN + 127) / 128, 256, 0, stream>>>(h2, wp2h, wp2l, dis, h1);
    aggregate_kernel<<<(NN + 3) / 4, 256, 0, stream>>>(cnt, sedge, dis, h1, b2, h2);
    ovf_kernel<<<256, 256, 0, stream>>>(ovf_cnt, ovf, dis, h1, h2);

    // ---- MLP head + softmax ----
    mlp_mfma_kernel<<<(NN + 127) / 128, 256, 0, stream>>>(h2, wpm1h, wpm1l, bm1, Wm2, bm2, out);
}

// Round 9
// 490.350 us; speedup vs baseline: 1.0338x; 1.0338x over previous
//
#include <hip/hip_runtime.h>
#include <math.h>

#define NN 100000
#define NE 3200000
#define INF 384
#define HID 64
#define CAP 48
#define OVF_CAP 65536
#define NBIN 391            // bin = col >> 8 (256 nodes per bin)
#define NREP 8              // replicas per bin (blockIdx & 7 ~ XCD id)
#define NCTR (NBIN * NREP)  // 3128
#define BCAP 1536           // fixed slots per (bin,rep); mean 1023, 16-sigma margin
#define EPB 8192            // edges per block (scatter chunk)
#define NBLK ((NE + EPB - 1) / EPB)  // 391

typedef unsigned long long ulong64;
typedef unsigned int uint32;
typedef unsigned short ushort16;
typedef __attribute__((ext_vector_type(8))) short bf16x8;
typedef __attribute__((ext_vector_type(4))) float f32x4;

__device__ inline float bf16_to_f(uint32 us) { return __uint_as_float(us << 16); }
__device__ inline ushort16 f_to_bf16(float f) {
    uint32 u = __float_as_uint(f);
    u += 0x7FFF + ((u >> 16) & 1);  // round-to-nearest-even
    return (ushort16)(u >> 16);
}
// split x into bf16 hi + bf16 lo (x ~= hi + lo, residual ~2^-17 relative)
__device__ inline void split_bf16(float x, ushort16& h, ushort16& l) {
    h = f_to_bf16(x);
    float hf = bf16_to_f((uint32)h);
    l = f_to_bf16(x - hf);
}

// direct-to-LDS DMA, 16B per lane. gptr is PER-LANE; lptr must be wave-uniform
// (HW writes lptr + lane*16). Loads consume no VGPRs -> cannot be serialized
// by register reuse; many stay in flight.
__device__ inline void gload_lds16(const float* g, float* l) {
    __builtin_amdgcn_global_load_lds(
        (const __attribute__((address_space(1))) void*)g,
        (__attribute__((address_space(3))) void*)l, 16, 0, 0);
}

// ---------------- setup: counters + W pre-split (fused, one launch) ----------
// bincur[i] = i*BCAP gives every (bin,rep) counter a fixed private region in
// ebin -- replaces binhist+binscan (uniform-random cols -> Poisson(1023) per
// counter vs capacity 1536 = 16 sigma).
// W layout: element (k,j) of W[K][64] -> ushort idx
//   ((k>>5)*4 + (j>>4))*64 + ((j&15) | (((k>>3)&3)<<4)) -> *8 + (k&7)
// so a wave's B-fragment load is one contiguous 1KB transaction.

__global__ __launch_bounds__(256) void setup_kernel(const float* __restrict__ W1,
                                                    const float* __restrict__ W2,
                                                    const float* __restrict__ Wm1,
                                                    ushort16* __restrict__ wp1h,
                                                    ushort16* __restrict__ wp1l,
                                                    ushort16* __restrict__ wp2h,
                                                    ushort16* __restrict__ wp2l,
                                                    ushort16* __restrict__ wpm1h,
                                                    ushort16* __restrict__ wpm1l,
                                                    int* __restrict__ ovf_cnt,
                                                    int* __restrict__ bincur) {
    int i = blockIdx.x * blockDim.x + threadIdx.x;
    int np = gridDim.x * blockDim.x;
    if (i == 0) *ovf_cnt = 0;
    for (int idx = i; idx < NCTR; idx += np) bincur[idx] = idx * BCAP;
    for (int idx = i; idx < INF * HID; idx += np) {
        int k = idx >> 6, j = idx & 63;
        ushort16 h, l;
        split_bf16(W1[idx], h, l);
        size_t dst = ((size_t)(((k >> 5) * 4 + (j >> 4)) * 64 +
                               ((j & 15) | (((k >> 3) & 3) << 4))) << 3) + (k & 7);
        wp1h[dst] = h;
        wp1l[dst] = l;
    }
    for (int idx = i; idx < HID * HID; idx += np) {
        int k = idx >> 6, j = idx & 63;
        size_t dst = ((size_t)(((k >> 5) * 4 + (j >> 4)) * 64 +
                               ((j & 15) | (((k >> 3) & 3) << 4))) << 3) + (k & 7);
        ushort16 h, l;
        split_bf16(W2[idx], h, l);
        wp2h[dst] = h;
        wp2l[dst] = l;
        split_bf16(Wm1[idx], h, l);
        wpm1h[dst] = h;
        wpm1l[dst] = l;
    }
}

// ---------------- scatter edges into fixed (bin,rep) regions ----------------

__global__ __launch_bounds__(1024) void binscatter_kernel(const int* __restrict__ row,
                                                          const int* __restrict__ col,
                                                          const float* __restrict__ ew,
                                                          int* __restrict__ bincur,
                                                          ulong64* __restrict__ ebin) {
    __shared__ int lhist[NBIN];
    __shared__ int lbase[NBIN];
    int tid = threadIdx.x;
    int rep = blockIdx.x & (NREP - 1);
    int base = blockIdx.x * EPB;
    if (tid < NBIN) lhist[tid] = 0;
    __syncthreads();
    int brk[8], rr[8];
    uint32 wb[8];
#pragma unroll
    for (int i = 0; i < 8; i++) {
        int e = base + i * 1024 + tid;
        brk[i] = -1;
        if (e < NE) {
            int r = row[e];
            int c = col[e];
            wb[i] = __float_as_uint(ew[e]);
            int b = c >> 8;
            int rk = atomicAdd(&lhist[b], 1);
            brk[i] = (b << 16) | rk;
            rr[i] = r | ((c & 255) << 17);
        }
    }
    __syncthreads();
    if (tid < NBIN && lhist[tid] > 0)
        lbase[tid] = atomicAdd(&bincur[tid * NREP + rep], lhist[tid]);
    __syncthreads();
#pragma unroll
    for (int i = 0; i < 8; i++) {
        if (brk[i] >= 0) {
            int b = brk[i] >> 16;
            int pos = lbase[b] + (brk[i] & 0xFFFF);
            int lim = (b * NREP + rep + 1) * BCAP;
            if (pos < lim)  // 16-sigma safety clamp, effectively never taken
                ebin[pos] = ((ulong64)wb[i] << 32) | (uint32)rr[i];
        }
    }
}

// ---------------- buckets + degree + dis (256-node bins, 8 segments) ---------
// Pads each node's sedge slots to a multiple of 8 with zeros so the aggregate
// can run an unguarded 8-wide loop (pad slots: w=0, r=0 -> contribute 0).

__global__ __launch_bounds__(256) void bucket_kernel(const int* __restrict__ bincur,
                                                     const ulong64* __restrict__ ebin,
                                                     ulong64* __restrict__ sedge,
                                                     int* __restrict__ cnt,
                                                     float* __restrict__ dis,
                                                     int* __restrict__ ovf_cnt,
                                                     int4* __restrict__ ovf) {
    __shared__ int cur[256];
    __shared__ float sdeg[256];
    int bin = blockIdx.x;
    int node0 = bin << 8;
    cur[threadIdx.x] = 0;
    sdeg[threadIdx.x] = 0.f;
    __syncthreads();
    for (int rep = 0; rep < NREP; rep++) {
        int ctr = bin * NREP + rep;
        int start = ctr * BCAP;
        int end = min(bincur[ctr], start + BCAP);
        for (int i = start + threadIdx.x; i < end; i += 256) {
            ulong64 pk = ebin[i];
            int r = (int)(pk & 0x1FFFF);
            int lc = (int)((pk >> 17) & 255);
            uint32 wb = (uint32)(pk >> 32);
            atomicAdd(&sdeg[lc], __uint_as_float(wb));   // LDS float atomic
            int rank = atomicAdd(&cur[lc], 1);           // LDS int atomic
            int node = node0 + lc;
            if (rank < CAP) {
                sedge[(size_t)node * CAP + rank] = ((ulong64)wb << 32) | (uint32)r;
            } else {
                int o = atomicAdd(ovf_cnt, 1);
                if (o < OVF_CAP) ovf[o] = make_int4(r, node, (int)wb, 0);
            }
        }
    }
    __syncthreads();
    int node = node0 + threadIdx.x;
    if (node < NN) {
        int cc = min(cur[threadIdx.x], CAP);
        cnt[node] = cc;
        int cpad = min((cc + 7) & ~7, CAP);
        for (int s = cc; s < cpad; s++) sedge[(size_t)node * CAP + s] = 0;
        dis[node] = rsqrtf(sdeg[threadIdx.x] + 1.0f);  // +1 self-loop
    }
}

// ---------------- MFMA GEMM: global_load_lds staged, double-buffered ---------
// hs_bf16[N x 64] = dis[N] * (act(A[N x K]) @ W).
// A staged via global_load_lds width=16 (DMA, zero VGPR -> loads stay in
// flight; rounds 2-8 showed the compiler serializes VGPR staging at ~1 TB/s).
// Tile: 64 rows x 64 K fp32, double-buffered (32 KB LDS), ONE barrier/tile:
//   STAGE(buf^1, t+1) issued BEFORE compute(buf) -> DMA overlaps ds_read+MFMA;
//   __syncthreads' vmcnt drain IS the buffer-ready condition.
// Bank conflicts: linear [64][64] tile would be 16-way on the frag ds_reads.
// Both-sides XOR swizzle (m201/m231): 16B unit j of row r holds GLOBAL chunk
// j^(r&7) (pre-swizzled per-lane SOURCE address, LDS dest stays linear);
// reads use unit m^(r&7). Result: exactly 8 lanes/group = b128 wave64 floor.
// Wave w owns rows 16w..16w+15 (M=16, N=64, 4 N-frags).
// mfma_f32_16x16x32_bf16: A row=lane&15, k=(lane>>4)*8+j; D col=lane&15,
// row=(lane>>4)*4+reg. 3-term split (Ah*Wh + Al*Wh + Ah*Wl), fp32 accum.

template <int K, bool LEAKY>
__global__ __launch_bounds__(256) void mfma_gemm_kernel(const float* __restrict__ A,
                                                        const ushort16* __restrict__ Wph,
                                                        const ushort16* __restrict__ Wpl,
                                                        const float* __restrict__ dis,
                                                        ushort16* __restrict__ out) {
    __shared__ float xs[2][64 * 64];
    const int tid = threadIdx.x;
    const int w = tid >> 6;
    const int l = tid & 63;
    const int lrow = l & 15;
    const int c4 = l >> 4;  // 0..3
    const int nb = blockIdx.x * 64;
    const bf16x8* __restrict__ Bh = (const bf16x8*)Wph;
    const bf16x8* __restrict__ Bl = (const bf16x8*)Wpl;

    // staging geometry: wave w stages rows 16w..16w+15 via 4 DMA instructions.
    // instr c: lane covers row 16w+4c+(l>>4), 16B-unit (l&15); source chunk is
    // pre-swizzled: (l&15) ^ (row&7).
    int srow[4], soff[4];
#pragma unroll
    for (int c = 0; c < 4; c++) {
        int r = w * 16 + c * 4 + (l >> 4);
        srow[c] = r;
        soff[c] = ((l & 15) ^ (r & 7)) * 4;  // float offset within row
    }

    f32x4 acc[4];
#pragma unroll
    for (int n = 0; n < 4; n++) acc[n] = (f32x4){0.f, 0.f, 0.f, 0.f};

    constexpr int NT = K / 64;
    const int R = w * 16 + lrow;       // row this lane computes
    const int sw = R & 7;              // read-side swizzle
    const float* __restrict__ lrowp = &xs[0][0] + (size_t)R * 64;

    // prologue: stage tile 0 into buf 0
#pragma unroll
    for (int c = 0; c < 4; c++) {
        int gr = min(nb + srow[c], NN - 1);
        gload_lds16(A + (size_t)gr * K + soff[c], &xs[0][(w * 16 + c * 4) * 64]);
    }
    __syncthreads();

    int cur = 0;
    for (int t = 0; t < NT; t++) {
        // ---- issue next tile's DMA (overlaps this tile's compute) ----
        if (t + 1 < NT) {
#pragma unroll
            for (int c = 0; c < 4; c++) {
                int gr = min(nb + srow[c], NN - 1);
                gload_lds16(A + (size_t)gr * K + (t + 1) * 64 + soff[c],
                            &xs[cur ^ 1][(w * 16 + c * 4) * 64]);
            }
        }
        const float* __restrict__ rp = lrowp + (size_t)cur * 64 * 64;
#pragma unroll
        for (int ks = 0; ks < 2; ks++) {
            int kslot = t * 2 + ks;
            // batch B loads (L2-hot 1KB wave-contiguous)
            bf16x8 bhc[4], blc[4];
#pragma unroll
            for (int n = 0; n < 4; n++) {
                bhc[n] = Bh[(size_t)(kslot * 4 + n) * 64 + l];
                blc[n] = Bl[(size_t)(kslot * 4 + n) * 64 + l];
            }
            // swizzled A-frag read: source chunks m, m+1 live at units m^sw, (m+1)^sw
            int m0 = ks * 8 + c4 * 2;
            float4 f0 = *(const float4*)(rp + ((m0 ^ sw) << 2));
            float4 f1 = *(const float4*)(rp + (((m0 + 1) ^ sw) << 2));
            float av[8] = {f0.x, f0.y, f0.z, f0.w, f1.x, f1.y, f1.z, f1.w};
            bf16x8 ah, al;
#pragma unroll
            for (int i = 0; i < 8; i++) {
                float x = av[i];
                if (LEAKY) x = x > 0.f ? x : 0.01f * x;
                ushort16 hh, ll;
                split_bf16(x, hh, ll);
                ah[i] = (short)hh;
                al[i] = (short)ll;
            }
#pragma unroll
            for (int n = 0; n < 4; n++) {
                acc[n] = __builtin_amdgcn_mfma_f32_16x16x32_bf16(ah, bhc[n], acc[n], 0, 0, 0);
                acc[n] = __builtin_amdgcn_mfma_f32_16x16x32_bf16(al, bhc[n], acc[n], 0, 0, 0);
                acc[n] = __builtin_amdgcn_mfma_f32_16x16x32_bf16(ah, blc[n], acc[n], 0, 0, 0);
            }
        }
        __syncthreads();  // drains DMA (next buf ready) + guards WAR on cur
        cur ^= 1;
    }
    // ---- epilogue: D col=lane&15, row=(lane>>4)*4+reg; scale by dis[node] ----
    int rbase = nb + w * 16 + (l >> 4) * 4;
#pragma unroll
    for (int r = 0; r < 4; r++) {
        int node = rbase + r;
        if (node < NN) {
            float ds = dis[node];
#pragma unroll
            for (int n = 0; n < 4; n++)
                out[(size_t)node * HID + n * 16 + lrow] = f_to_bf16(acc[n][r] * ds);
        }
    }
}

// ---------------- bucket aggregate: wave per node, lane = feature ----------------
// hs is dis-prescaled bf16. n is made provably wave-uniform via readfirstlane
// so the 8-slot packet loads become scalar-cache loads; packet j+1's scalar
// loads issue before packet j's gathers.
// out[n] = bias + dis[n] * (hs[n] + sum_j w_j * hs[r_j])

__global__ __launch_bounds__(256) void aggregate_kernel(const int* __restrict__ cnt,
                                                        const ulong64* __restrict__ sedge,
                                                        const float* __restrict__ dis,
                                                        const ushort16* __restrict__ hs,
                                                        const float* __restrict__ bias,
                                                        float* __restrict__ out) {
    int lane = threadIdx.x & 63;
    int wslot = __builtin_amdgcn_readfirstlane(threadIdx.x >> 6);
    int n = blockIdx.x * 4 + wslot;
    if (n >= NN) return;
    int c = cnt[n];                      // uniform -> scalar load
    int cpad = (c + 7) & ~7;
    float dn = dis[n];                   // uniform -> scalar load
    const ulong64* __restrict__ el = sedge + (size_t)n * CAP;

    float acc = bf16_to_f((uint32)hs[(size_t)n * HID + lane]);  // self term
    if (cpad > 0) {
        ulong64 p[8];
#pragma unroll
        for (int i = 0; i < 8; i++) p[i] = el[i];
        int j = 0;
        for (;;) {
            int jn = j + 8;
            bool more = jn < cpad;
            ulong64 q[8];
            if (more) {
#pragma unroll
                for (int i = 0; i < 8; i++) q[i] = el[jn + i];
            }
            float v[8], wv[8];
#pragma unroll
            for (int i = 0; i < 8; i++) {
                uint32 r = (uint32)p[i];
                wv[i] = __uint_as_float((uint32)(p[i] >> 32));  // 0 for pad slots
                v[i] = bf16_to_f((uint32)hs[(size_t)r * HID + lane]);
            }
#pragma unroll
            for (int i = 0; i < 8; i++) acc = fmaf(wv[i], v[i], acc);
            if (!more) break;
            j = jn;
#pragma unroll
            for (int i = 0; i < 8; i++) p[i] = q[i];
        }
    }
    out[(size_t)n * HID + lane] = fmaf(dn, acc, bias[lane]);
}

// ---------------- overflow edges: rare, fp32 atomics ----------------
// hs is dis-prescaled: contribution = dis[dst] * w * hs[src]

__global__ __launch_bounds__(256) void ovf_kernel(const int* __restrict__ ovf_cnt,
                                                  const int4* __restrict__ ovf,
                                                  const float* __restrict__ dis,
                                                  const ushort16* __restrict__ hs,
                                                  float* __restrict__ out) {
    int lane = threadIdx.x & 63;
    int wid = blockIdx.x * 4 + (threadIdx.x >> 6);
    int nw = gridDim.x * 4;
    int c = min(*ovf_cnt, OVF_CAP);
    for (int i = wid; i < c; i += nw) {
        int4 t = ovf[i];
        float w = __int_as_float(t.z);
        float nrm = w * dis[t.y];
        atomicAdd(&out[(size_t)t.y * HID + lane],
                  nrm * bf16_to_f((uint32)hs[(size_t)t.x * HID + lane]));
    }
}

// ---------------- MLP head + softmax (no LDS, deep pipeline) -----------------
// agg[N x 64] -> (ELU(agg@Wm1 + bm1)) @ Wm2 + bm2 -> softmax(2).
// M=32/wave; K=64 so ALL 16 B-fragment pairs preload up front; all 8 A float4
// batched.

__global__ __launch_bounds__(256, 3) void mlp_mfma_kernel(const float* __restrict__ agg,
                                                          const ushort16* __restrict__ Wph,
                                                          const ushort16* __restrict__ Wpl,
                                                          const float* __restrict__ bm1,
                                                          const float* __restrict__ Wm2,
                                                          const float* __restrict__ bm2,
                                                          float* __restrict__ out) {
    const int tid = threadIdx.x;
    const int w = tid >> 6;
    const int l = tid & 63;
    const int lrow = l & 15;
    const int kq = (l >> 4) * 8;
    const int nb = blockIdx.x * 128;
    const int wr = nb + w * 32;
    const bf16x8* __restrict__ Bh = (const bf16x8*)Wph;
    const bf16x8* __restrict__ Bl = (const bf16x8*)Wpl;
    const float* __restrict__ ar0 = agg + (size_t)min(wr + lrow, NN - 1) * HID + kq;
    const float* __restrict__ ar1 = agg + (size_t)min(wr + 16 + lrow, NN - 1) * HID + kq;

    // preload ALL B fragments (K=64 -> 8 pairs) and all A
    bf16x8 bh[8], bl[8];
#pragma unroll
    for (int s = 0; s < 8; s++) {
        bh[s] = Bh[(size_t)s * 64 + l];
        bl[s] = Bl[(size_t)s * 64 + l];
    }
    float4 a[2][4];
#pragma unroll
    for (int m = 0; m < 2; m++) {
        const float* ar = m ? ar1 : ar0;
        a[m][0] = *(const float4*)(ar);
        a[m][1] = *(const float4*)(ar + 4);
        a[m][2] = *(const float4*)(ar + 32);
        a[m][3] = *(const float4*)(ar + 36);
    }

    f32x4 acc[2][4];
#pragma unroll
    for (int m = 0; m < 2; m++)
#pragma unroll
        for (int n = 0; n < 4; n++) acc[m][n] = (f32x4){0.f, 0.f, 0.f, 0.f};

#pragma unroll
    for (int ks = 0; ks < 2; ks++) {
        bf16x8 ah[2], al[2];
#pragma unroll
        for (int m = 0; m < 2; m++) {
            float4 x0 = a[m][ks * 2], x1 = a[m][ks * 2 + 1];
            float av[8] = {x0.x, x0.y, x0.z, x0.w, x1.x, x1.y, x1.z, x1.w};
#pragma unroll
            for (int i = 0; i < 8; i++) {
                ushort16 hh, ll;
                split_bf16(av[i], hh, ll);
                ah[m][i] = (short)hh;
                al[m][i] = (short)ll;
            }
        }
#pragma unroll
        for (int n = 0; n < 4; n++)
#pragma unroll
            for (int m = 0; m < 2; m++) {
                acc[m][n] = __builtin_amdgcn_mfma_f32_16x16x32_bf16(ah[m], bh[ks * 4 + n], acc[m][n], 0, 0, 0);
                acc[m][n] = __builtin_amdgcn_mfma_f32_16x16x32_bf16(al[m], bh[ks * 4 + n], acc[m][n], 0, 0, 0);
                acc[m][n] = __builtin_amdgcn_mfma_f32_16x16x32_bf16(ah[m], bl[ks * 4 + n], acc[m][n], 0, 0, 0);
            }
    }

    // per-lane constants for the 4 columns this lane owns
    float b1c[4], w2a[4], w2b[4];
#pragma unroll
    for (int n = 0; n < 4; n++) {
        int colw = n * 16 + lrow;
        b1c[n] = bm1[colw];
        w2a[n] = Wm2[colw * 2];
        w2b[n] = Wm2[colw * 2 + 1];
    }
    float b20 = bm2[0], b21 = bm2[1];

#pragma unroll
    for (int m = 0; m < 2; m++)
#pragma unroll
        for (int r = 0; r < 4; r++) {
            float s0 = 0.f, s1 = 0.f;
#pragma unroll
            for (int n = 0; n < 4; n++) {
                float u = acc[m][n][r] + b1c[n];
                u = u > 0.f ? u : (expf(u) - 1.f);  // ELU
                s0 = fmaf(u, w2a[n], s0);
                s1 = fmaf(u, w2b[n], s1);
            }
#pragma unroll
            for (int off = 1; off < 16; off <<= 1) {
                s0 += __shfl_xor(s0, off);
                s1 += __shfl_xor(s1, off);
            }
            int node = wr + m * 16 + (l >> 4) * 4 + r;
            if (lrow == 0 && node < NN) {
                float l0 = s0 + b20, l1 = s1 + b21;
                float mx = fmaxf(l0, l1);
                float e0 = expf(l0 - mx), e1 = expf(l1 - mx);
                float inv = 1.f / (e0 + e1);
                *(float2*)&out[(size_t)node * 2] = make_float2(e0 * inv, e1 * inv);
            }
        }
}

// ---------------- launch ----------------

extern "C" void kernel_launch(void* const* d_in, const int* in_sizes, int n_in,
                              void* d_out, int out_size, void* d_ws, size_t ws_size,
                              hipStream_t stream) {
    const float* X   = (const float*)d_in[0];
    const int*   ei  = (const int*)d_in[1];
    const float* ew  = (const float*)d_in[2];
    const float* W1  = (const float*)d_in[3];
    const float* b1  = (const float*)d_in[4];
    const float* W2  = (const float*)d_in[5];
    const float* b2  = (const float*)d_in[6];
    const float* Wm1 = (const float*)d_in[7];
    const float* bm1 = (const float*)d_in[8];
    const float* Wm2 = (const float*)d_in[9];
    const float* bm2 = (const float*)d_in[10];
    const int* row = ei;
    const int* col = ei + NE;
    float* out = (float*)d_out;

    const size_t MB = 1024 * 1024;
    const size_t KB = 1024;
    char* ws = (char*)d_ws;
    float*    dis     = (float*)   (ws + 0 * MB);           // NN floats (0.4 MB)
    int*      cnt     = (int*)     (ws + 1 * MB);           // NN ints   (0.4 MB)
    ushort16* wp1h    = (ushort16*)(ws + 2 * MB);           // 48 KB (frag-order)
    ushort16* wp1l    = (ushort16*)(ws + 2 * MB + 64 * KB);
    ushort16* wp2h    = (ushort16*)(ws + 2 * MB + 128 * KB);// 8 KB
    ushort16* wp2l    = (ushort16*)(ws + 2 * MB + 144 * KB);
    ushort16* wpm1h   = (ushort16*)(ws + 2 * MB + 160 * KB);// 8 KB
    ushort16* wpm1l   = (ushort16*)(ws + 2 * MB + 176 * KB);
    int*      ovf_cnt = (int*)     (ws + 3 * MB);           // 1 int
    int*      bincur  = (int*)     (ws + 3 * MB + 16 * KB); // NCTR ints
    int4*     ovf     = (int4*)    (ws + 4 * MB);           // OVF_CAP*16 (1 MB)
    ulong64*  ebin    = (ulong64*) (ws + 5 * MB);           // NCTR*BCAP*8 = 38.4 MB
    float*    h2      = (float*)   (ws + 5 * MB);           // fp32 (25.6MB), overlays ebin
    ulong64*  sedge   = (ulong64*) (ws + 44 * MB);          // NN*CAP*8 = 38.4 MB
    ushort16* h1      = (ushort16*)(ws + 83 * MB);          // NN*64 bf16 (12.8 MB)

    // ---- setup (counters + W pre-split) + direct-alloc scatter + buckets ----
    setup_kernel<<<64, 256, 0, stream>>>(W1, W2, Wm1, wp1h, wp1l, wp2h, wp2l,
                                         wpm1h, wpm1l, ovf_cnt, bincur);
    binscatter_kernel<<<NBLK, 1024, 0, stream>>>(row, col, ew, bincur, ebin);
    bucket_kernel<<<NBIN, 256, 0, stream>>>(bincur, ebin, sedge, cnt, dis, ovf_cnt, ovf);

    // ---- conv1 ----
    mfma_gemm_kernel<INF, false><<<(NN + 63) / 64, 256, 0, stream>>>(X, wp1h, wp1l, dis, h1);
    aggregate_kernel<<<(NN + 3) / 4, 256, 0, stream>>>(cnt, sedge, dis, h1, b1, h2);
    ovf_kernel<<<256, 256, 0, stream>>>(ovf_cnt, ovf, dis, h1, h2);

    // ---- conv2 ----
    mfma_gemm_kernel<HID, true><<<(NN + 63) / 64, 256, 0, stream>>>(h2, wp2h, wp2l, dis, h1);
    aggregate_kernel<<<(NN + 3) / 4, 256, 0, stream>>>(cnt, sedge, dis, h1, b2, h2);
    ovf_kernel<<<256, 256, 0, stream>>>(ovf_cnt, ovf, dis, h1, h2);

    // ---- MLP head + softmax ----
    mlp_mfma_kernel<<<(NN + 127) / 128, 256, 0, stream>>>(h2, wpm1h, wpm1l, bm1, Wm2, bm2, out);
}